// Round 10
// baseline (191.890 us; speedup 1.0000x reference)
//
#include <hip/hip_runtime.h>

#define LOG2E 1.4426950408889634f

typedef __bf16 bf16x8 __attribute__((ext_vector_type(8)));
typedef float f32x4 __attribute__((ext_vector_type(4)));
typedef float f32x2 __attribute__((ext_vector_type(2)));
typedef unsigned short u16x8 __attribute__((ext_vector_type(8)));

__device__ __forceinline__ unsigned short bfb(__bf16 b){
  union { __bf16 b; unsigned short u; } z; z.b = b; return z.u;
}

// Packed-B layout: element (n,k) hi/lo -> ((nt*16+ks)*2+hl)*512 + lane*8 + j
//   nt=n>>4, ln=n&15, ks=k>>5, q=(k&31)>>3, j=k&7, lane=q*16+ln

// ---------------- prep: W2 fold, Wv/Wo split, biases, A-planes (q/k/v -> bf16 hi/lo) ----
__global__ __launch_bounds__(256) void prep_all(
    const float* __restrict__ Wq, const float* __restrict__ Aq,
    const float* __restrict__ Wk, const float* __restrict__ Ak,
    const float* __restrict__ bq, const float* __restrict__ bk,
    const float* __restrict__ av,
    const float* __restrict__ Wv, const float* __restrict__ Wo,
    const float* __restrict__ Qin, const float* __restrict__ Kin,
    const float* __restrict__ Vin,
    unsigned short* __restrict__ W2qp, unsigned short* __restrict__ W2kp,
    unsigned short* __restrict__ Wvp,  unsigned short* __restrict__ Wop,
    unsigned short* __restrict__ qhi, unsigned short* __restrict__ qlo,
    unsigned short* __restrict__ khi, unsigned short* __restrict__ klo,
    unsigned short* __restrict__ vhi, unsigned short* __restrict__ vlo,
    float* __restrict__ b2q, float* __restrict__ b2k, float* __restrict__ av2g){
  if (blockIdx.x >= 513){
    // ---- A-plane conversion: f32 -> bf16 hi/lo, 8 elems/thread ----
    if (blockIdx.y) return;
    int j = blockIdx.x - 513;                 // 0..767
    const float* src; unsigned short *dh, *dl;
    if (j < 256){ src = Qin; dh = qhi; dl = qlo; }
    else if (j < 512){ src = Kin; dh = khi; dl = klo; j -= 256; }
    else { src = Vin; dh = vhi; dl = vlo; j -= 512; }
    int base = (j * 256 + threadIdx.x) * 8;
    f32x4 v0 = *(const f32x4*)(src + base);
    f32x4 v1 = *(const f32x4*)(src + base + 4);
    u16x8 hh, ll;
    #pragma unroll
    for (int t = 0; t < 8; t++){
      float f = (t < 4) ? v0[t] : v1[t - 4];
      __bf16 hb = (__bf16)f;
      hh[t] = bfb(hb);
      ll[t] = bfb((__bf16)(f - (float)hb));
    }
    *(u16x8*)(dh + base) = hh;
    *(u16x8*)(dl + base) = ll;
    return;
  }
  if (blockIdx.x >= 256){
    if (blockIdx.x == 512){
      if (blockIdx.y == 0){
        #pragma unroll
        for (int rep = 0; rep < 2; rep++){
          int n = rep * 256 + threadIdx.x;
          int h = n >> 6, e = n & 63;
          float aq = 0.f, ak = 0.f;
          for (int c = 0; c < 64; c++){
            aq += Aq[e*64 + c] * bq[h*64 + c];
            ak += Ak[e*64 + c] * bk[h*64 + c];
          }
          b2q[n] = aq * (2.f * LOG2E);
          b2k[n] = ak * (2.f * LOG2E);
        }
      } else {
        if (threadIdx.x < 64) av2g[threadIdx.x] = -2.f * LOG2E * av[threadIdx.x];
      }
      return;
    }
    const float* src = blockIdx.y ? Wo : Wv;
    unsigned short* dst = blockIdx.y ? Wop : Wvp;
    int base = ((blockIdx.x - 256) * 256 + threadIdx.x) * 4;
    int n = base >> 9, k0 = base & 511;
    float4 v = *(const float4*)(src + base);
    ushort4 h, l;
    float f; __bf16 hb;
    f = v.x; hb = (__bf16)f; h.x = bfb(hb); l.x = bfb((__bf16)(f - (float)hb));
    f = v.y; hb = (__bf16)f; h.y = bfb(hb); l.y = bfb((__bf16)(f - (float)hb));
    f = v.z; hb = (__bf16)f; h.z = bfb(hb); l.z = bfb((__bf16)(f - (float)hb));
    f = v.w; hb = (__bf16)f; h.w = bfb(hb); l.w = bfb((__bf16)(f - (float)hb));
    int nt = n >> 4, ln = n & 15;
    int ks = k0 >> 5, q = (k0 & 31) >> 3, j0 = k0 & 7;
    size_t off = (size_t)((nt*16 + ks) * 2) * 512 + (q*16 + ln) * 8 + j0;
    *(ushort4*)(dst + off)       = h;
    *(ushort4*)(dst + off + 512) = l;
    return;
  }
  // W2 fold: idx -> (n, 4 consecutive k)
  const float* W  = blockIdx.y ? Wk : Wq;
  const float* Am = blockIdx.y ? Ak : Aq;
  unsigned short* dst = blockIdx.y ? W2kp : W2qp;
  int idx = blockIdx.x * 256 + threadIdx.x;   // 0..65535
  int n = idx >> 7;                            // 0..511 (wave-uniform)
  int k0 = (idx & 127) * 4;                    // 0..508 step 4
  int h = n >> 6, e = n & 63;
  float4 acc = {0.f, 0.f, 0.f, 0.f};
  #pragma unroll 8
  for (int c = 0; c < 64; c++){
    float am = Am[e*64 + c];
    float4 wv = *(const float4*)(W + (size_t)(h*64 + c)*512 + k0);
    acc.x += am * wv.x;
    acc.y += am * wv.y;
    acc.z += am * wv.z;
    acc.w += am * wv.w;
  }
  int nt = n >> 4, ln = n & 15;
  int ks = k0 >> 5, q = (k0 & 31) >> 3, j0 = k0 & 7;
  size_t off = (size_t)((nt*16 + ks) * 2) * 512 + (q*16 + ln) * 8 + j0;
  ushort4 hh, ll;
  float f; __bf16 hb;
  f = acc.x * (2.f * LOG2E); hb = (__bf16)f; hh.x = bfb(hb); ll.x = bfb((__bf16)(f - (float)hb));
  f = acc.y * (2.f * LOG2E); hb = (__bf16)f; hh.y = bfb(hb); ll.y = bfb((__bf16)(f - (float)hb));
  f = acc.z * (2.f * LOG2E); hb = (__bf16)f; hh.z = bfb(hb); ll.z = bfb((__bf16)(f - (float)hb));
  f = acc.w * (2.f * LOG2E); hb = (__bf16)f; hh.w = bfb(hb); ll.w = bfb((__bf16)(f - (float)hb));
  *(ushort4*)(dst + off)       = hh;
  *(ushort4*)(dst + off + 512) = ll;
}

// ---------------- MFMA GEMM: reg-double-buffered A (pre-split bf16 planes), packed B ----
struct GemmBatch {
  const unsigned short* Ahi;
  const unsigned short* Alo;
  const unsigned short* Bp;
  const float* bias;
  float* Cf;
  unsigned short* Chi;           // dual-plane transposed output (V)
  unsigned short* Clo;
  int transposed;                // 1: eqQ [bh][q][d] f32; 2: ekT [bh][d][j] f32
  int expout;                    // 1: store exp2(val)
  int dual;                      // 1: transposed dual-plane bf16 [bh][d][j]
};
struct GemmArgs { GemmBatch g[3]; };

__global__ __launch_bounds__(256) void gemm_nk(GemmArgs ga){
  GemmBatch gb = ga.g[blockIdx.z];
  __shared__ unsigned short AhiS[64 * 40];   // staging 32x72 fits; dual-epilogue needs 64x40
  __shared__ unsigned short AloS[64 * 40];
  __shared__ float TfS[64 * 40];             // f32 transposed epilogue (ekT)
  const int tid = threadIdx.x, lane = tid & 63, w = tid >> 6;
  const int l15 = lane & 15, quad = lane >> 4;
  const int m0  = blockIdx.x * 32;
  const int nt0 = blockIdx.y * 4;
  const int wr = w >> 1, wc = w & 1;
  f32x4 ac0 = {0.f,0.f,0.f,0.f}, ac1 = ac0;

  const int srow = tid >> 3;            // 0..31
  const int scol = (tid & 7) * 8;       // 0..56
  const unsigned short* srcH = gb.Ahi + (size_t)(m0 + srow) * 512 + scol;
  const unsigned short* srcL = gb.Alo + (size_t)(m0 + srow) * 512 + scol;
  unsigned short* dstH = &AhiS[srow * 72 + scol];
  unsigned short* dstL = &AloS[srow * 72 + scol];
  u16x8 ph = *(const u16x8*)srcH;       // kc=0 prefetch
  u16x8 pl = *(const u16x8*)srcL;

  const int arow = (wr * 16 + l15) * 72;

  for (int kc = 0; kc < 8; kc++){
    __syncthreads();
    *(u16x8*)dstH = ph;
    *(u16x8*)dstL = pl;
    if (kc < 7){
      ph = *(const u16x8*)(srcH + (kc + 1) * 64);   // latency spans compute phase
      pl = *(const u16x8*)(srcL + (kc + 1) * 64);
    }
    __syncthreads();
    #pragma unroll
    for (int s = 0; s < 2; s++){
      int ks = kc * 2 + s;
      bf16x8 ah = *(const bf16x8*)&AhiS[arow + s*32 + quad*8];
      bf16x8 al = *(const bf16x8*)&AloS[arow + s*32 + quad*8];
      #pragma unroll
      for (int t = 0; t < 2; t++){
        int nt = nt0 + wc*2 + t;
        const unsigned short* bp = gb.Bp + (size_t)((nt*16 + ks) * 2) * 512 + lane*8;
        bf16x8 bh = *(const bf16x8*)bp;
        bf16x8 bl = *(const bf16x8*)(bp + 512);
        f32x4& ac = t ? ac1 : ac0;
        ac = __builtin_amdgcn_mfma_f32_16x16x32_bf16(ah, bh, ac, 0, 0, 0);
        ac = __builtin_amdgcn_mfma_f32_16x16x32_bf16(al, bh, ac, 0, 0, 0);
        ac = __builtin_amdgcn_mfma_f32_16x16x32_bf16(ah, bl, ac, 0, 0, 0);
      }
    }
  }

  if (gb.dual){
    // stage [n_local][m_local] bf16 planes in LDS, then coalesced 16B writes
    __syncthreads();
    #pragma unroll
    for (int t = 0; t < 2; t++){
      f32x4 v = t ? ac1 : ac0;
      int nl = wc*32 + t*16 + l15;
      float bs = gb.bias[nt0*16 + nl];
      #pragma unroll
      for (int r = 0; r < 4; r++){
        float val = v[r] + bs;
        int ml = wr*16 + quad*4 + r;
        __bf16 hb = (__bf16)val;
        AhiS[nl*40 + ml] = bfb(hb);
        AloS[nl*40 + ml] = bfb((__bf16)(val - (float)hb));
      }
    }
    __syncthreads();
    int nl = tid >> 2, mq = (tid & 3) * 8;
    int hh2 = (nt0 * 16) >> 6;
    int b2 = m0 >> 9;
    size_t o = (size_t)((b2*8 + hh2)*64 + ((nt0*16 + nl) & 63)) * 512 + (m0 & 511) + mq;
    *(u16x8*)(gb.Chi + o) = *(const u16x8*)&AhiS[nl*40 + mq];
    *(u16x8*)(gb.Clo + o) = *(const u16x8*)&AloS[nl*40 + mq];
    return;
  }

  if (gb.transposed == 2){
    // ekT f32 [bh][d][j]: stage [n_local][m_local] in LDS, coalesced f32x4 writes
    __syncthreads();
    #pragma unroll
    for (int t = 0; t < 2; t++){
      f32x4 v = t ? ac1 : ac0;
      int nl = wc*32 + t*16 + l15;
      float bs = gb.bias[nt0*16 + nl];
      #pragma unroll
      for (int r = 0; r < 4; r++){
        float val = v[r] + bs;
        if (gb.expout) val = __builtin_amdgcn_exp2f(val);
        int ml = wr*16 + quad*4 + r;
        TfS[nl*40 + ml] = val;
      }
    }
    __syncthreads();
    int nl = tid >> 2, mq = (tid & 3) * 8;
    int hh2 = (nt0 * 16) >> 6;
    int b2 = m0 >> 9;
    size_t o = (size_t)((b2*8 + hh2)*64 + ((nt0*16 + nl) & 63)) * 512 + (m0 & 511) + mq;
    *(f32x4*)(gb.Cf + o)     = *(const f32x4*)&TfS[nl*40 + mq];
    *(f32x4*)(gb.Cf + o + 4) = *(const f32x4*)&TfS[nl*40 + mq + 4];
    return;
  }

  const int mrow = m0 + wr * 16 + quad * 4;
  #pragma unroll
  for (int t = 0; t < 2; t++){
    f32x4 v = t ? ac1 : ac0;
    int n = nt0*16 + wc*32 + t*16 + l15;
    float bs = gb.bias[n];
    #pragma unroll
    for (int r = 0; r < 4; r++){
      float val = v[r] + bs;
      if (gb.expout) val = __builtin_amdgcn_exp2f(val);
      int m2 = mrow + r;
      if (gb.transposed){
        // eqQ layout: [bh][q][d], bh=(m2>>9)*8+(n>>6), q=m2&511, d=n&63
        gb.Cf[(size_t)(((m2 >> 9) * 8 + (n >> 6)) * 512 + (m2 & 511)) * 64 + (n & 63)] = val;
      } else {
        gb.Cf[(size_t)m2 * 512 + n] = val;
      }
    }
  }
}

// ---------------- fused additive-attention core: global EK/V, LDS only for eq/P ------
// 1024 threads / 16 waves: 1 q-row per wave, 4-way k-split PV.
// EK read per-lane from ekT [bh][d][j]; V fragments from dual bf16 planes.
// All 16 waves read the same 32KB EK/V chunks -> L1-served; LDS pipe freed.
__global__ __launch_bounds__(1024, 8) void attn_kernel(
    const float* __restrict__ eqQ, const float* __restrict__ ekT,
    const float* __restrict__ av2g,
    const unsigned short* __restrict__ vthi, const unsigned short* __restrict__ vtlo,
    unsigned short* __restrict__ Ohhi, unsigned short* __restrict__ Ohlo){
  __shared__ unsigned short pcb[2 * 16 * 136];
  __shared__ float dn[16];
  __shared__ float eqs[16 * 64];
  __shared__ float avs[64];
  __shared__ float cmb[12 * 256];

  const int tid = threadIdx.x, lane = tid & 63, w = tid >> 6;   // w in 0..15
  const int l15 = lane & 15, quad = lane >> 4;
  const int bh = blockIdx.y;
  const int i0 = blockIdx.x * 16;
  const int r0 = __builtin_amdgcn_readfirstlane(w);
  const int ntile = w & 3, kq = w >> 2;                         // kq in 0..3
  const size_t ebase = (size_t)bh * 64 * 512;                   // ekT / V plane base
  const size_t obase = (size_t)(bh >> 3) * 512 * 512 + (size_t)(bh & 7) * 64;

  float den = 0.f;
  f32x4 Cacc = {0.f, 0.f, 0.f, 0.f};

  // init: stage eq rows + av
  eqs[w * 64 + lane] = eqQ[((size_t)bh * 512 + i0 + w) * 64 + lane];
  if (w == 0) avs[lane] = av2g[lane];
  __syncthreads();

  for (int c = 0; c < 4; c++){
    // ---- X: score from global ekT (L1-shared across waves), publish P ----
    const float* ekc = ekT + ebase + c * 128 + 2 * lane;
    f32x2 sacc = {0.f, 0.f};
    #pragma unroll 4
    for (int d = 0; d < 64; d += 4){
      f32x4 eq4 = *(const f32x4*)&eqs[r0 * 64 + d];    // LDS broadcast
      f32x4 a4  = *(const f32x4*)&avs[d];              // LDS broadcast
      f32x2 ek0 = *(const f32x2*)(ekc + (size_t)(d    ) * 512);
      f32x2 ek1 = *(const f32x2*)(ekc + (size_t)(d + 1) * 512);
      f32x2 ek2 = *(const f32x2*)(ekc + (size_t)(d + 2) * 512);
      f32x2 ek3 = *(const f32x2*)(ekc + (size_t)(d + 3) * 512);
      f32x2 A = __builtin_elementwise_fma((f32x2){eq4[0], eq4[0]}, ek0, (f32x2){1.f, 1.f});
      f32x2 B = __builtin_elementwise_fma((f32x2){eq4[1], eq4[1]}, ek1, (f32x2){1.f, 1.f});
      f32x2 t = __builtin_elementwise_fma((f32x2){a4[1], a4[1]}, A, (f32x2){a4[0], a4[0]} * B);
      f32x2 dpr = A * B;
      f32x2 r;
      r.x = __builtin_amdgcn_rcpf(dpr.x);
      r.y = __builtin_amdgcn_rcpf(dpr.y);
      sacc = __builtin_elementwise_fma(t, r, sacc);
      f32x2 C = __builtin_elementwise_fma((f32x2){eq4[2], eq4[2]}, ek2, (f32x2){1.f, 1.f});
      f32x2 D = __builtin_elementwise_fma((f32x2){eq4[3], eq4[3]}, ek3, (f32x2){1.f, 1.f});
      f32x2 t2 = __builtin_elementwise_fma((f32x2){a4[3], a4[3]}, C, (f32x2){a4[2], a4[2]} * D);
      f32x2 dpr2 = C * D;
      f32x2 r2;
      r2.x = __builtin_amdgcn_rcpf(dpr2.x);
      r2.y = __builtin_amdgcn_rcpf(dpr2.y);
      sacc = __builtin_elementwise_fma(t2, r2, sacc);
    }
    float e0 = __builtin_amdgcn_exp2f(sacc.x);
    float e1 = __builtin_amdgcn_exp2f(sacc.y);
    den += e0 + e1;
    {
      __bf16 h0 = (__bf16)e0, h1 = (__bf16)e1;
      ushort2 hi = { bfb(h0), bfb(h1) };
      ushort2 lo = { bfb((__bf16)(e0 - (float)h0)), bfb((__bf16)(e1 - (float)h1)) };
      *(ushort2*)&pcb[(0*16 + r0) * 136 + 2*lane] = hi;
      *(ushort2*)&pcb[(1*16 + r0) * 136 + 2*lane] = lo;
    }
    __syncthreads();

    // ---- Y: PV MFMA, V fragments straight from global dual planes ----
    {
      int k0 = kq * 32 + quad * 8;
      bf16x8 ph = *(const bf16x8*)&pcb[(0*16 + l15) * 136 + k0];
      bf16x8 pl = *(const bf16x8*)&pcb[(1*16 + l15) * 136 + k0];
      size_t vo = ebase + (size_t)(ntile * 16 + l15) * 512 + c * 128 + k0;
      bf16x8 vh = *(const bf16x8*)(vthi + vo);
      bf16x8 vl = *(const bf16x8*)(vtlo + vo);
      Cacc = __builtin_amdgcn_mfma_f32_16x16x32_bf16(ph, vh, Cacc, 0, 0, 0);
      Cacc = __builtin_amdgcn_mfma_f32_16x16x32_bf16(pl, vh, Cacc, 0, 0, 0);
      Cacc = __builtin_amdgcn_mfma_f32_16x16x32_bf16(ph, vl, Cacc, 0, 0, 0);
    }
    __syncthreads();   // all P reads done before next chunk overwrites pcb
  }

  #pragma unroll
  for (int off = 1; off < 64; off <<= 1)
    den += __shfl_xor(den, off, 64);
  if (lane == 0) dn[r0] = den;
  if (kq > 0){
    #pragma unroll
    for (int r = 0; r < 4; r++) cmb[(w - 4) * 256 + lane * 4 + r] = Cacc[r];
  }
  __syncthreads();
  if (kq == 0){
    #pragma unroll
    for (int r = 0; r < 4; r++){
      float cv = Cacc[r];
      #pragma unroll
      for (int j = 0; j < 3; j++) cv += cmb[(j*4 + ntile) * 256 + lane * 4 + r];
      int row = quad * 4 + r;
      int d = ntile * 16 + l15;
      float val = cv / dn[row];
      __bf16 hb = (__bf16)val;
      size_t oi = obase + (size_t)(i0 + row) * 512 + d;
      Ohhi[oi] = bfb(hb);
      Ohlo[oi] = bfb((__bf16)(val - (float)hb));
    }
  }
}

// ---------------- launch ----------------
extern "C" void kernel_launch(void* const* d_in, const int* in_sizes, int n_in,
                              void* d_out, int out_size, void* d_ws, size_t ws_size,
                              hipStream_t stream){
  const float* q_in = (const float*)d_in[0];
  const float* k_in = (const float*)d_in[1];
  const float* v_in = (const float*)d_in[2];
  const float* Wq_  = (const float*)d_in[3];
  const float* bq_  = (const float*)d_in[4];
  const float* Wk_  = (const float*)d_in[5];
  const float* bk_  = (const float*)d_in[6];
  const float* Wv_  = (const float*)d_in[7];
  const float* bv_  = (const float*)d_in[8];
  const float* Wo_  = (const float*)d_in[9];
  const float* bo_  = (const float*)d_in[10];
  const float* Aq_  = (const float*)d_in[11];
  const float* Ak_  = (const float*)d_in[12];
  const float* av_  = (const float*)d_in[13];

  char* ws = (char*)d_ws;
  unsigned short* W2qp = (unsigned short*)(ws + 0);
  unsigned short* W2kp = (unsigned short*)(ws + 1048576);
  unsigned short* Ohhi = (unsigned short*)(ws + 0);        // reuses W2 region after gemm1
  unsigned short* Ohlo = (unsigned short*)(ws + 1048576);
  unsigned short* Wvp  = (unsigned short*)(ws + 2097152);
  unsigned short* Wop  = (unsigned short*)(ws + 3145728);
  float* b2q  = (float*)(ws + 4194304);
  float* b2k  = (float*)(ws + 4196352);
  float* av2g = (float*)(ws + 4198400);
  float* eqQ  = (float*)(ws + 4198656);                    // 2MB [bh][q][d] f32
  float* ekT  = (float*)(ws + 6295808);                    // 2MB [bh][d][j] f32
  unsigned short* vthi = (unsigned short*)(ws + 8392960);  // 1MB [bh][d][j] bf16 hi
  unsigned short* vtlo = (unsigned short*)(ws + 9441536);  // 1MB lo
  unsigned short* qhi = (unsigned short*)(ws + 10490112);
  unsigned short* qlo = (unsigned short*)(ws + 11538688);
  unsigned short* khi = (unsigned short*)(ws + 12587264);
  unsigned short* klo = (unsigned short*)(ws + 13635840);
  unsigned short* vhi = (unsigned short*)(ws + 14684416);
  unsigned short* vlo = (unsigned short*)(ws + 15732992);

  prep_all<<<dim3(1281, 2, 1), 256, 0, stream>>>(Wq_, Aq_, Wk_, Ak_, bq_, bk_, av_,
                                                 Wv_, Wo_, q_in, k_in, v_in,
                                                 W2qp, W2kp, Wvp, Wop,
                                                 qhi, qlo, khi, klo, vhi, vlo,
                                                 b2q, b2k, av2g);

  GemmArgs ga;
  ga.g[0] = { qhi, qlo, W2qp, b2q, eqQ, 0, 0, 1, 1, 0 };
  ga.g[1] = { khi, klo, W2kp, b2k, ekT, 0, 0, 2, 1, 0 };
  ga.g[2] = { vhi, vlo, Wvp,  bv_, 0, vthi, vtlo, 0, 0, 1 };
  gemm_nk<<<dim3(32, 8, 3), 256, 0, stream>>>(ga);

  attn_kernel<<<dim3(32, 16, 1), 1024, 0, stream>>>(eqQ, ekT, av2g, vthi, vtlo, Ohhi, Ohlo);

  GemmArgs go;
  go.g[0] = { Ohhi, Ohlo, Wop, bo_, (float*)d_out, 0, 0, 0, 0, 0 };
  go.g[1] = go.g[0];
  go.g[2] = go.g[0];
  gemm_nk<<<dim3(32, 8, 1), 256, 0, stream>>>(go);
}

// Round 11
// 149.738 us; speedup vs baseline: 1.2815x; 1.2815x over previous
//
#include <hip/hip_runtime.h>

#define LOG2E 1.4426950408889634f

typedef __bf16 bf16x8 __attribute__((ext_vector_type(8)));
typedef float f32x4 __attribute__((ext_vector_type(4)));
typedef float f32x2 __attribute__((ext_vector_type(2)));
typedef unsigned short u16x8 __attribute__((ext_vector_type(8)));

__device__ __forceinline__ unsigned short bfb(__bf16 b){
  union { __bf16 b; unsigned short u; } z; z.b = b; return z.u;
}

// Packed-B layout: element (n,k) hi/lo -> ((nt*16+ks)*2+hl)*512 + lane*8 + j
//   nt=n>>4, ln=n&15, ks=k>>5, q=(k&31)>>3, j=k&7, lane=q*16+ln

// ---------------- prep: W2 fold, Wv/Wo split, biases, A-planes (q/k/v -> bf16 hi/lo) ----
__global__ __launch_bounds__(256) void prep_all(
    const float* __restrict__ Wq, const float* __restrict__ Aq,
    const float* __restrict__ Wk, const float* __restrict__ Ak,
    const float* __restrict__ bq, const float* __restrict__ bk,
    const float* __restrict__ av,
    const float* __restrict__ Wv, const float* __restrict__ Wo,
    const float* __restrict__ Qin, const float* __restrict__ Kin,
    const float* __restrict__ Vin,
    unsigned short* __restrict__ W2qp, unsigned short* __restrict__ W2kp,
    unsigned short* __restrict__ Wvp,  unsigned short* __restrict__ Wop,
    unsigned short* __restrict__ qhi, unsigned short* __restrict__ qlo,
    unsigned short* __restrict__ khi, unsigned short* __restrict__ klo,
    unsigned short* __restrict__ vhi, unsigned short* __restrict__ vlo,
    float* __restrict__ b2q, float* __restrict__ b2k, float* __restrict__ av2g){
  if (blockIdx.x >= 513){
    // ---- A-plane conversion: f32 -> bf16 hi/lo, 8 elems/thread ----
    if (blockIdx.y) return;
    int j = blockIdx.x - 513;                 // 0..767
    const float* src; unsigned short *dh, *dl;
    if (j < 256){ src = Qin; dh = qhi; dl = qlo; }
    else if (j < 512){ src = Kin; dh = khi; dl = klo; j -= 256; }
    else { src = Vin; dh = vhi; dl = vlo; j -= 512; }
    int base = (j * 256 + threadIdx.x) * 8;
    f32x4 v0 = *(const f32x4*)(src + base);
    f32x4 v1 = *(const f32x4*)(src + base + 4);
    u16x8 hh, ll;
    #pragma unroll
    for (int t = 0; t < 8; t++){
      float f = (t < 4) ? v0[t] : v1[t - 4];
      __bf16 hb = (__bf16)f;
      hh[t] = bfb(hb);
      ll[t] = bfb((__bf16)(f - (float)hb));
    }
    *(u16x8*)(dh + base) = hh;
    *(u16x8*)(dl + base) = ll;
    return;
  }
  if (blockIdx.x >= 256){
    if (blockIdx.x == 512){
      if (blockIdx.y == 0){
        #pragma unroll
        for (int rep = 0; rep < 2; rep++){
          int n = rep * 256 + threadIdx.x;
          int h = n >> 6, e = n & 63;
          float aq = 0.f, ak = 0.f;
          for (int c = 0; c < 64; c++){
            aq += Aq[e*64 + c] * bq[h*64 + c];
            ak += Ak[e*64 + c] * bk[h*64 + c];
          }
          b2q[n] = aq * (2.f * LOG2E);
          b2k[n] = ak * (2.f * LOG2E);
        }
      } else {
        if (threadIdx.x < 64) av2g[threadIdx.x] = -2.f * LOG2E * av[threadIdx.x];
      }
      return;
    }
    const float* src = blockIdx.y ? Wo : Wv;
    unsigned short* dst = blockIdx.y ? Wop : Wvp;
    int base = ((blockIdx.x - 256) * 256 + threadIdx.x) * 4;
    int n = base >> 9, k0 = base & 511;
    float4 v = *(const float4*)(src + base);
    ushort4 h, l;
    float f; __bf16 hb;
    f = v.x; hb = (__bf16)f; h.x = bfb(hb); l.x = bfb((__bf16)(f - (float)hb));
    f = v.y; hb = (__bf16)f; h.y = bfb(hb); l.y = bfb((__bf16)(f - (float)hb));
    f = v.z; hb = (__bf16)f; h.z = bfb(hb); l.z = bfb((__bf16)(f - (float)hb));
    f = v.w; hb = (__bf16)f; h.w = bfb(hb); l.w = bfb((__bf16)(f - (float)hb));
    int nt = n >> 4, ln = n & 15;
    int ks = k0 >> 5, q = (k0 & 31) >> 3, j0 = k0 & 7;
    size_t off = (size_t)((nt*16 + ks) * 2) * 512 + (q*16 + ln) * 8 + j0;
    *(ushort4*)(dst + off)       = h;
    *(ushort4*)(dst + off + 512) = l;
    return;
  }
  // W2 fold: idx -> (n, 4 consecutive k)
  const float* W  = blockIdx.y ? Wk : Wq;
  const float* Am = blockIdx.y ? Ak : Aq;
  unsigned short* dst = blockIdx.y ? W2kp : W2qp;
  int idx = blockIdx.x * 256 + threadIdx.x;   // 0..65535
  int n = idx >> 7;                            // 0..511 (wave-uniform)
  int k0 = (idx & 127) * 4;                    // 0..508 step 4
  int h = n >> 6, e = n & 63;
  float4 acc = {0.f, 0.f, 0.f, 0.f};
  #pragma unroll 8
  for (int c = 0; c < 64; c++){
    float am = Am[e*64 + c];
    float4 wv = *(const float4*)(W + (size_t)(h*64 + c)*512 + k0);
    acc.x += am * wv.x;
    acc.y += am * wv.y;
    acc.z += am * wv.z;
    acc.w += am * wv.w;
  }
  int nt = n >> 4, ln = n & 15;
  int ks = k0 >> 5, q = (k0 & 31) >> 3, j0 = k0 & 7;   // q, j0 valid for all 4 k's
  size_t off = (size_t)((nt*16 + ks) * 2) * 512 + (q*16 + ln) * 8 + j0;
  ushort4 hh, ll;
  float f; __bf16 hb;
  f = acc.x * (2.f * LOG2E); hb = (__bf16)f; hh.x = bfb(hb); ll.x = bfb((__bf16)(f - (float)hb));
  f = acc.y * (2.f * LOG2E); hb = (__bf16)f; hh.y = bfb(hb); ll.y = bfb((__bf16)(f - (float)hb));
  f = acc.z * (2.f * LOG2E); hb = (__bf16)f; hh.z = bfb(hb); ll.z = bfb((__bf16)(f - (float)hb));
  f = acc.w * (2.f * LOG2E); hb = (__bf16)f; hh.w = bfb(hb); ll.w = bfb((__bf16)(f - (float)hb));
  *(ushort4*)(dst + off)       = hh;
  *(ushort4*)(dst + off + 512) = ll;
}

// ---------------- MFMA GEMM: reg-double-buffered A (pre-split bf16 planes), packed B ----
// M-tile 32, grid (32, 8, z). 4 waves: w>>1 = row strip, w&1 = col half (2 nt each).
struct GemmBatch {
  const unsigned short* Ahi;
  const unsigned short* Alo;
  const unsigned short* Bp;
  const float* bias;
  float* Cf;
  int transposed;                // 1: eqQ layout [bh][q][d] contiguous
  int expout;                    // 1: store exp2(val)
};
struct GemmArgs { GemmBatch g[3]; };

__global__ __launch_bounds__(256) void gemm_nk(GemmArgs ga){
  GemmBatch gb = ga.g[blockIdx.z];
  __shared__ unsigned short AhiS[32 * 72];
  __shared__ unsigned short AloS[32 * 72];
  const int tid = threadIdx.x, lane = tid & 63, w = tid >> 6;
  const int l15 = lane & 15, quad = lane >> 4;
  const int m0  = blockIdx.x * 32;
  const int nt0 = blockIdx.y * 4;
  const int wr = w >> 1, wc = w & 1;
  f32x4 ac0 = {0.f,0.f,0.f,0.f}, ac1 = ac0;

  const int srow = tid >> 3;            // 0..31
  const int scol = (tid & 7) * 8;       // 0..56
  const unsigned short* srcH = gb.Ahi + (size_t)(m0 + srow) * 512 + scol;
  const unsigned short* srcL = gb.Alo + (size_t)(m0 + srow) * 512 + scol;
  unsigned short* dstH = &AhiS[srow * 72 + scol];
  unsigned short* dstL = &AloS[srow * 72 + scol];
  u16x8 ph = *(const u16x8*)srcH;       // kc=0 prefetch
  u16x8 pl = *(const u16x8*)srcL;

  const int arow = (wr * 16 + l15) * 72;

  for (int kc = 0; kc < 8; kc++){
    __syncthreads();
    *(u16x8*)dstH = ph;
    *(u16x8*)dstL = pl;
    if (kc < 7){
      ph = *(const u16x8*)(srcH + (kc + 1) * 64);   // latency spans compute phase
      pl = *(const u16x8*)(srcL + (kc + 1) * 64);
    }
    __syncthreads();
    #pragma unroll
    for (int s = 0; s < 2; s++){
      int ks = kc * 2 + s;
      bf16x8 ah = *(const bf16x8*)&AhiS[arow + s*32 + quad*8];
      bf16x8 al = *(const bf16x8*)&AloS[arow + s*32 + quad*8];
      #pragma unroll
      for (int t = 0; t < 2; t++){
        int nt = nt0 + wc*2 + t;
        const unsigned short* bp = gb.Bp + (size_t)((nt*16 + ks) * 2) * 512 + lane*8;
        bf16x8 bh = *(const bf16x8*)bp;
        bf16x8 bl = *(const bf16x8*)(bp + 512);
        f32x4& ac = t ? ac1 : ac0;
        ac = __builtin_amdgcn_mfma_f32_16x16x32_bf16(ah, bh, ac, 0, 0, 0);
        ac = __builtin_amdgcn_mfma_f32_16x16x32_bf16(al, bh, ac, 0, 0, 0);
        ac = __builtin_amdgcn_mfma_f32_16x16x32_bf16(ah, bl, ac, 0, 0, 0);
      }
    }
  }

  const int mrow = m0 + wr * 16 + quad * 4;
  #pragma unroll
  for (int t = 0; t < 2; t++){
    f32x4 v = t ? ac1 : ac0;
    int n = nt0*16 + wc*32 + t*16 + l15;
    float bs = gb.bias[n];
    #pragma unroll
    for (int r = 0; r < 4; r++){
      float val = v[r] + bs;
      if (gb.expout) val = __builtin_amdgcn_exp2f(val);
      int m2 = mrow + r;
      if (gb.transposed){
        // eqQ layout: [bh][q][d], bh=(m2>>9)*8+(n>>6), q=m2&511, d=n&63
        gb.Cf[(size_t)(((m2 >> 9) * 8 + (n >> 6)) * 512 + (m2 & 511)) * 64 + (n & 63)] = val;
      } else {
        gb.Cf[(size_t)m2 * 512 + n] = val;
      }
    }
  }
}

// ---------------- fused additive-attention core (factored-exp score, MFMA PV) ------------
// 1024 threads / 16 waves: 1 q-row per wave, 4-way k-split PV.
// eq/av staged in LDS once (chunk-invariant); EK prefetched 2 phases deep.
// Epilogue writes Oh as bf16 hi/lo planes (feeds the A-plane gemm directly).
__global__ __launch_bounds__(1024, 8) void attn_kernel(
    const float* __restrict__ eqQ, const float* __restrict__ ekp,
    const float* __restrict__ Vv, const float* __restrict__ av2g,
    unsigned short* __restrict__ Ohhi, unsigned short* __restrict__ Ohlo){
  __shared__ float bufA[64 * 130];
  __shared__ float bufB[64 * 130];
  __shared__ unsigned short pcb[2 * 16 * 136];
  __shared__ float dn[16];
  __shared__ float eqs[16 * 64];
  __shared__ float avs[64];
  float* cmb = bufA;

  const int tid = threadIdx.x, lane = tid & 63, w = tid >> 6;   // w in 0..15
  const int l15 = lane & 15, quad = lane >> 4;
  const int bh = blockIdx.y;
  const int i0 = blockIdx.x * 16;
  const size_t kbase = (size_t)(bh >> 3) * 512 * 512 + (size_t)(bh & 7) * 64;
  const int r0 = __builtin_amdgcn_readfirstlane(w);
  const int ntile = w & 3, kq = w >> 2;                         // kq in 0..3

  float den = 0.f;
  f32x4 Cacc = {0.f, 0.f, 0.f, 0.f};

  { // init: stage eq rows + av + EK_0 -> LDS
    eqs[w * 64 + lane] = eqQ[((size_t)bh * 512 + i0 + w) * 64 + lane];
    if (w == 0) avs[lane] = av2g[lane];
    #pragma unroll
    for (int m = 0; m < 4; m++){
      int i = w + 16 * m;
      float a = ekp[kbase + (size_t)(2*i    ) * 512 + lane];
      float b = ekp[kbase + (size_t)(2*i + 1) * 512 + lane];
      *(float2*)&bufA[lane * 130 + 2*i] = make_float2(a, b);
    }
  }
  __syncthreads();

  for (int c = 0; c < 4; c++){
    // ---- X: V_c + EK_{c+1} global->regs (deep prefetch), score from bufA, publish P ----
    float va[4], vb[4], ka[4], kb[4];
    #pragma unroll
    for (int m = 0; m < 4; m++){
      int i = w + 16 * m;
      va[m] = Vv[kbase + (size_t)(c*128 + 2*i    ) * 512 + lane];
      vb[m] = Vv[kbase + (size_t)(c*128 + 2*i + 1) * 512 + lane];
    }
    if (c < 3){
      #pragma unroll
      for (int m = 0; m < 4; m++){
        int i = w + 16 * m;
        ka[m] = ekp[kbase + (size_t)((c+1)*128 + 2*i    ) * 512 + lane];
        kb[m] = ekp[kbase + (size_t)((c+1)*128 + 2*i + 1) * 512 + lane];
      }
    }
    f32x2 sacc = {0.f, 0.f};
    #pragma unroll 4
    for (int d = 0; d < 64; d += 4){
      f32x4 eq4 = *(const f32x4*)&eqs[r0 * 64 + d];    // LDS broadcast
      f32x4 a4  = *(const f32x4*)&avs[d];              // LDS broadcast
      f32x2 ek0 = *(const f32x2*)&bufA[(d  ) * 130 + 2 * lane];
      f32x2 ek1 = *(const f32x2*)&bufA[(d+1) * 130 + 2 * lane];
      f32x2 ek2 = *(const f32x2*)&bufA[(d+2) * 130 + 2 * lane];
      f32x2 ek3 = *(const f32x2*)&bufA[(d+3) * 130 + 2 * lane];
      f32x2 A = __builtin_elementwise_fma((f32x2){eq4[0], eq4[0]}, ek0, (f32x2){1.f, 1.f});
      f32x2 B = __builtin_elementwise_fma((f32x2){eq4[1], eq4[1]}, ek1, (f32x2){1.f, 1.f});
      f32x2 t = __builtin_elementwise_fma((f32x2){a4[1], a4[1]}, A, (f32x2){a4[0], a4[0]} * B);
      f32x2 dpr = A * B;
      f32x2 r;
      r.x = __builtin_amdgcn_rcpf(dpr.x);
      r.y = __builtin_amdgcn_rcpf(dpr.y);
      sacc = __builtin_elementwise_fma(t, r, sacc);
      f32x2 C = __builtin_elementwise_fma((f32x2){eq4[2], eq4[2]}, ek2, (f32x2){1.f, 1.f});
      f32x2 D = __builtin_elementwise_fma((f32x2){eq4[3], eq4[3]}, ek3, (f32x2){1.f, 1.f});
      f32x2 t2 = __builtin_elementwise_fma((f32x2){a4[3], a4[3]}, C, (f32x2){a4[2], a4[2]} * D);
      f32x2 dpr2 = C * D;
      f32x2 r2;
      r2.x = __builtin_amdgcn_rcpf(dpr2.x);
      r2.y = __builtin_amdgcn_rcpf(dpr2.y);
      sacc = __builtin_elementwise_fma(t2, r2, sacc);
    }
    float e0 = __builtin_amdgcn_exp2f(sacc.x);
    float e1 = __builtin_amdgcn_exp2f(sacc.y);
    den += e0 + e1;
    {
      __bf16 h0 = (__bf16)e0, h1 = (__bf16)e1;
      ushort2 hi = { bfb(h0), bfb(h1) };
      ushort2 lo = { bfb((__bf16)(e0 - (float)h0)), bfb((__bf16)(e1 - (float)h1)) };
      *(ushort2*)&pcb[(0*16 + r0) * 136 + 2*lane] = hi;
      *(ushort2*)&pcb[(1*16 + r0) * 136 + 2*lane] = lo;
    }
    #pragma unroll
    for (int m = 0; m < 4; m++){
      int i = w + 16 * m;
      *(float2*)&bufB[lane * 130 + 2*i] = make_float2(va[m], vb[m]);
    }
    __syncthreads();

    // ---- Y: PV MFMA from bufB/pcb, EK_{c+1} (already in regs) -> bufA ----
    {
      int k0 = kq * 32 + quad * 8;
      bf16x8 ph = *(const bf16x8*)&pcb[(0*16 + l15) * 136 + k0];
      bf16x8 pl = *(const bf16x8*)&pcb[(1*16 + l15) * 136 + k0];
      const float* vp = &bufB[(ntile*16 + l15) * 130 + k0];
      bf16x8 vh, vl;
      #pragma unroll
      for (int j = 0; j < 8; j++){
        float f = vp[j];
        __bf16 h = (__bf16)f;
        vh[j] = h; vl[j] = (__bf16)(f - (float)h);
      }
      Cacc = __builtin_amdgcn_mfma_f32_16x16x32_bf16(ph, vh, Cacc, 0, 0, 0);
      Cacc = __builtin_amdgcn_mfma_f32_16x16x32_bf16(pl, vh, Cacc, 0, 0, 0);
      Cacc = __builtin_amdgcn_mfma_f32_16x16x32_bf16(ph, vl, Cacc, 0, 0, 0);
    }
    if (c < 3){
      #pragma unroll
      for (int m = 0; m < 4; m++){
        int i = w + 16 * m;
        *(float2*)&bufA[lane * 130 + 2*i] = make_float2(ka[m], kb[m]);
      }
    }
    __syncthreads();
  }

  #pragma unroll
  for (int off = 1; off < 64; off <<= 1)
    den += __shfl_xor(den, off, 64);
  if (lane == 0) dn[r0] = den;
  if (kq > 0){
    #pragma unroll
    for (int r = 0; r < 4; r++) cmb[(w - 4) * 256 + lane * 4 + r] = Cacc[r];
  }
  __syncthreads();
  if (kq == 0){
    #pragma unroll
    for (int r = 0; r < 4; r++){
      float cv = Cacc[r];
      #pragma unroll
      for (int j = 0; j < 3; j++) cv += cmb[(j*4 + ntile) * 256 + lane * 4 + r];
      int row = quad * 4 + r;
      int d = ntile * 16 + l15;
      float val = cv / dn[row];
      __bf16 hb = (__bf16)val;
      size_t oi = kbase + (size_t)(i0 + row) * 512 + d;
      Ohhi[oi] = bfb(hb);
      Ohlo[oi] = bfb((__bf16)(val - (float)hb));
    }
  }
}

// ---------------- launch ----------------
extern "C" void kernel_launch(void* const* d_in, const int* in_sizes, int n_in,
                              void* d_out, int out_size, void* d_ws, size_t ws_size,
                              hipStream_t stream){
  const float* q_in = (const float*)d_in[0];
  const float* k_in = (const float*)d_in[1];
  const float* v_in = (const float*)d_in[2];
  const float* Wq_  = (const float*)d_in[3];
  const float* bq_  = (const float*)d_in[4];
  const float* Wk_  = (const float*)d_in[5];
  const float* bk_  = (const float*)d_in[6];
  const float* Wv_  = (const float*)d_in[7];
  const float* bv_  = (const float*)d_in[8];
  const float* Wo_  = (const float*)d_in[9];
  const float* bo_  = (const float*)d_in[10];
  const float* Aq_  = (const float*)d_in[11];
  const float* Ak_  = (const float*)d_in[12];
  const float* av_  = (const float*)d_in[13];

  char* ws = (char*)d_ws;
  unsigned short* W2qp = (unsigned short*)(ws + 0);
  unsigned short* W2kp = (unsigned short*)(ws + 1048576);
  unsigned short* Ohhi = (unsigned short*)(ws + 0);        // reuses W2 region after gemm1
  unsigned short* Ohlo = (unsigned short*)(ws + 1048576);
  unsigned short* Wvp  = (unsigned short*)(ws + 2097152);
  unsigned short* Wop  = (unsigned short*)(ws + 3145728);
  float* b2q  = (float*)(ws + 4194304);
  float* b2k  = (float*)(ws + 4196352);
  float* av2g = (float*)(ws + 4198400);
  float* eqQ  = (float*)(ws + 4198656);
  float* ekp  = (float*)(ws + 6295808);
  float* Vw   = (float*)(ws + 8392960);
  unsigned short* qhi = (unsigned short*)(ws + 10490112);
  unsigned short* qlo = (unsigned short*)(ws + 11538688);
  unsigned short* khi = (unsigned short*)(ws + 12587264);
  unsigned short* klo = (unsigned short*)(ws + 13635840);
  unsigned short* vhi = (unsigned short*)(ws + 14684416);
  unsigned short* vlo = (unsigned short*)(ws + 15732992);

  prep_all<<<dim3(1281, 2, 1), 256, 0, stream>>>(Wq_, Aq_, Wk_, Ak_, bq_, bk_, av_,
                                                 Wv_, Wo_, q_in, k_in, v_in,
                                                 W2qp, W2kp, Wvp, Wop,
                                                 qhi, qlo, khi, klo, vhi, vlo,
                                                 b2q, b2k, av2g);

  GemmArgs ga;
  ga.g[0] = { qhi, qlo, W2qp, b2q, eqQ, 1, 1 };
  ga.g[1] = { khi, klo, W2kp, b2k, ekp, 0, 1 };
  ga.g[2] = { vhi, vlo, Wvp,  bv_, Vw,  0, 0 };
  gemm_nk<<<dim3(32, 8, 3), 256, 0, stream>>>(ga);

  attn_kernel<<<dim3(32, 16, 1), 1024, 0, stream>>>(eqQ, ekp, Vw, av2g, Ohhi, Ohlo);

  GemmArgs go;
  go.g[0] = { Ohhi, Ohlo, Wop, bo_, (float*)d_out, 1, 0 };
  go.g[1] = go.g[0];
  go.g[2] = go.g[0];
  go.g[0].transposed = 0;
  go.g[1] = go.g[0];
  go.g[2] = go.g[0];
  gemm_nk<<<dim3(32, 8, 1), 256, 0, stream>>>(go);
}